// Round 13
// baseline (178.331 us; speedup 1.0000x reference)
//
#include <hip/hip_runtime.h>
#include <hip/hip_bf16.h>

#define DEV __device__ __forceinline__

typedef unsigned short u16;
typedef unsigned int u32;
typedef __attribute__((ext_vector_type(8))) short short8;
typedef __attribute__((ext_vector_type(4))) float f32x4;
typedef __attribute__((ext_vector_type(4), aligned(4))) float f32x4u;  // 4B-aligned vector load

DEV u16 f2bf(float f) {
  __hip_bfloat16 h = __float2bfloat16(f);   // RNE
  return *(u16*)&h;
}
DEV float bf2f_s(short s) { return __uint_as_float(((u32)(u16)s) << 16); }

#define NB 8
#define NH 6
#define CTOT 192
#define HW 16384
#define VTS 34     // k3 LDS n-row stride (u16): 17 dwords, coprime 32 banks

// ---------------------------------------------------------------------------
// KCONV v3: depthwise 3x3 conv, streaming, barrier-free, LDS-free, SHUFFLE-FREE.
// R11/R12 stuck at 100us with VALUBusy 24%, VGPR 28: per-row chain
// load(vmcnt) -> shfl x2 (ds_bpermute, lgkmcnt) -> conv defeated all
// source-level pipelining. Fix: lane i loads px{2i-1..2i+2} directly as a
// 4B-aligned float4 (misaligned-16 OK on gfx950) -> no cross-lane ops at all;
// edge lanes clamp the address and shift components in-register.
// wave = (class, b, channel, 32-row stripe); tasks interleaved q/kv per block.
// ---------------------------------------------------------------------------
DEV float4 ldrow(const float* __restrict__ in, int ar, int lane) {
  if (ar < 0 || ar >= 128) return make_float4(0.f, 0.f, 0.f, 0.f);
  const float* rp = in + ar * 128;
  const int off  = 2 * lane - 1;
  const int offc = (lane == 0) ? 0 : ((lane == 63) ? 124 : off);
  f32x4u v = *(const f32x4u*)(rp + offc);
  float4 r = make_float4(v[0], v[1], v[2], v[3]);
  if (lane == 0)  r = make_float4(0.f, v[0], v[1], v[2]);   // {-1,0,1,2} with pad
  if (lane == 63) r = make_float4(v[1], v[2], v[3], 0.f);   // {125,126,127,pad}
  return r;
}

__global__ __launch_bounds__(256) void kconv(
    const float* __restrict__ x, const float* __restrict__ y,
    const float* __restrict__ wdw,
    u16* __restrict__ qws, u16* __restrict__ kws, u16* __restrict__ vws)
{
  const int t = threadIdx.x, lane = t & 63, w = t >> 6;
  const int tid  = blockIdx.x * 4 + w;   // 12288 wave-tasks
  const int iskv = tid & 1;              // interleave q/kv within each block
  const int task = tid >> 1;             // 0..6143
  const int b   = task / 768;
  const int rem = task - b * 768;
  const int gc  = rem >> 2;              // channel 0..191
  const int rg  = rem & 3;               // 32-row stripe
  const int r0  = rg * 32;

  const float* __restrict__ in =
      (iskv ? y : x) + (((size_t)(b * CTOT + gc)) << 14);

  float w0[9], w1[9];
  if (!iskv) {
#pragma unroll
    for (int i = 0; i < 9; ++i) w0[i] = wdw[gc * 9 + i];
  } else {
#pragma unroll
    for (int i = 0; i < 9; ++i) {
      w0[i] = wdw[(CTOT + gc) * 9 + i];       // k
      w1[i] = wdw[(2 * CTOT + gc) * 9 + i];   // v
    }
  }

  u16* __restrict__ out0 =
      (iskv ? kws : qws) + (((size_t)(b * CTOT + gc)) << 14);
  u16* __restrict__ out1 = vws + (((size_t)(b * CTOT + gc)) << 14);

  // taps: px0 uses (x,y,z), px1 uses (y,z,w) of each row's float4
  #define CONVROW(r, rm, rc, rp_) { \
      float o0, o1; \
      o0 = w0[0] * (rm).x; o0 = fmaf(w0[1], (rm).y, o0); o0 = fmaf(w0[2], (rm).z, o0); \
      o0 = fmaf(w0[3], (rc).x, o0); o0 = fmaf(w0[4], (rc).y, o0); o0 = fmaf(w0[5], (rc).z, o0); \
      o0 = fmaf(w0[6], (rp_).x, o0); o0 = fmaf(w0[7], (rp_).y, o0); o0 = fmaf(w0[8], (rp_).z, o0); \
      o1 = w0[0] * (rm).y; o1 = fmaf(w0[1], (rm).z, o1); o1 = fmaf(w0[2], (rm).w, o1); \
      o1 = fmaf(w0[3], (rc).y, o1); o1 = fmaf(w0[4], (rc).z, o1); o1 = fmaf(w0[5], (rc).w, o1); \
      o1 = fmaf(w0[6], (rp_).y, o1); o1 = fmaf(w0[7], (rp_).z, o1); o1 = fmaf(w0[8], (rp_).w, o1); \
      ((u32*)(out0 + (r) * 128))[lane] = ((u32)f2bf(o1) << 16) | (u32)f2bf(o0); \
      if (iskv) { \
        float v0, v1; \
        v0 = w1[0] * (rm).x; v0 = fmaf(w1[1], (rm).y, v0); v0 = fmaf(w1[2], (rm).z, v0); \
        v0 = fmaf(w1[3], (rc).x, v0); v0 = fmaf(w1[4], (rc).y, v0); v0 = fmaf(w1[5], (rc).z, v0); \
        v0 = fmaf(w1[6], (rp_).x, v0); v0 = fmaf(w1[7], (rp_).y, v0); v0 = fmaf(w1[8], (rp_).z, v0); \
        v1 = w1[0] * (rm).y; v1 = fmaf(w1[1], (rm).z, v1); v1 = fmaf(w1[2], (rm).w, v1); \
        v1 = fmaf(w1[3], (rc).y, v1); v1 = fmaf(w1[4], (rc).z, v1); v1 = fmaf(w1[5], (rc).w, v1); \
        v1 = fmaf(w1[6], (rp_).y, v1); v1 = fmaf(w1[7], (rp_).z, v1); v1 = fmaf(w1[8], (rp_).w, v1); \
        ((u32*)(out1 + (r) * 128))[lane] = ((u32)f2bf(v1) << 16) | (u32)f2bf(v0); \
      } }

  float4 ring[4];                 // slot(ar) = (ar - r0 + 1) & 3
  ring[0] = ldrow(in, r0 - 1, lane);
  ring[1] = ldrow(in, r0,     lane);
  ring[2] = ldrow(in, r0 + 1, lane);

#pragma unroll 4
  for (int rr = 0; rr < 32; ++rr) {
    const int r = r0 + rr;
    ring[(rr + 3) & 3] = ldrow(in, r + 2, lane);   // prefetch (used next iter)
    const float4 rm = ring[rr & 3];
    const float4 rc = ring[(rr + 1) & 3];
    const float4 rp = ring[(rr + 2) & 3];
    CONVROW(r, rm, rc, rp);
  }
  #undef CONVROW
}

// ---------------------------------------------------------------------------
// K2a (verified R3): per (b,head) gram[c][d] = sum_n q[c][n]*k[d][n] via MFMA,
// plus sum-of-squares. grid 48x16 p-tiles, f32-atomic partials (pre-zeroed).
// ---------------------------------------------------------------------------
__global__ __launch_bounds__(256) void k2a_gram(
    const u16* __restrict__ qws, const u16* __restrict__ kws,
    float* __restrict__ gram, float* __restrict__ sqq, float* __restrict__ sqk)
{
  const int t = threadIdx.x, l = t & 63, w = t >> 6;
  const int bh = blockIdx.x >> 4, tile = blockIdx.x & 15;
  const int p0 = tile * 1024 + w * 256;
  const u16* qb = qws + (((size_t)bh) << 19);
  const u16* kb = kws + (((size_t)bh) << 19);
  const int row = l & 15;
  const int kq  = (l >> 4) * 8;

  f32x4 acc[2][2] = {};
  float sq[2] = {0.f, 0.f}, sk[2] = {0.f, 0.f};

  for (int ks = 0; ks < 8; ++ks) {
    const int p = p0 + ks * 32 + kq;
    short8 av[2], bv[2];
#pragma unroll
    for (int tc = 0; tc < 2; ++tc) {
      av[tc] = *(const short8*)(qb + (((size_t)(tc * 16 + row)) << 14) + p);
      bv[tc] = *(const short8*)(kb + (((size_t)(tc * 16 + row)) << 14) + p);
    }
#pragma unroll
    for (int tc = 0; tc < 2; ++tc) {
#pragma unroll
      for (int j = 0; j < 8; ++j) {
        float fa = bf2f_s(av[tc][j]); sq[tc] = fmaf(fa, fa, sq[tc]);
        float fb = bf2f_s(bv[tc][j]); sk[tc] = fmaf(fb, fb, sk[tc]);
      }
    }
#pragma unroll
    for (int tc = 0; tc < 2; ++tc)
#pragma unroll
      for (int td = 0; td < 2; ++td)
        acc[tc][td] = __builtin_amdgcn_mfma_f32_16x16x32_bf16(av[tc], bv[td], acc[tc][td], 0, 0, 0);
  }

#pragma unroll
  for (int tc = 0; tc < 2; ++tc)
#pragma unroll
    for (int td = 0; td < 2; ++td)
#pragma unroll
      for (int rr = 0; rr < 4; ++rr) {
        int c = tc * 16 + (l >> 4) * 4 + rr;
        int d = td * 16 + row;
        atomicAdd(gram + (size_t)bh * 1024 + c * 32 + d, acc[tc][td][rr]);
      }

#pragma unroll
  for (int tc = 0; tc < 2; ++tc) {
    sq[tc] += __shfl_xor(sq[tc], 16);
    sq[tc] += __shfl_xor(sq[tc], 32);
    sk[tc] += __shfl_xor(sk[tc], 16);
    sk[tc] += __shfl_xor(sk[tc], 32);
  }
  if ((l >> 4) == 0) {
#pragma unroll
    for (int tc = 0; tc < 2; ++tc) {
      atomicAdd(sqq + bh * 32 + tc * 16 + row, sq[tc]);
      atomicAdd(sqk + bh * 32 + tc * 16 + row, sk[tc]);
    }
  }
}

// ---------------------------------------------------------------------------
// K2b: logits = gram/(|q||k|)*temp, row-softmax, fold 1x1 proj:
//   W2[b][o][h*32+d] = sum_c wp[o][h*32+c] * A[c][d]  (bf16 out)
// ---------------------------------------------------------------------------
__global__ __launch_bounds__(256) void k2b_w2(
    const float* __restrict__ gram, const float* __restrict__ sqq,
    const float* __restrict__ sqk, const float* __restrict__ wp,
    const float* __restrict__ temp, u16* __restrict__ W2)
{
  __shared__ float Ls[32][33];
  __shared__ float As[32][33];
  __shared__ float wl[192 * 32];
  __shared__ float nq[32], nk[32];
  const int t = threadIdx.x;
  const int bh = blockIdx.x, b = bh / 6, h = bh % 6;
  const float tmp = temp[h];
  if (t < 32) nq[t] = fmaxf(sqrtf(sqq[bh * 32 + t]), 1e-12f);
  else if (t < 64) nk[t - 32] = fmaxf(sqrtf(sqk[bh * 32 + t - 32]), 1e-12f);
  __syncthreads();
#pragma unroll
  for (int i = 0; i < 4; ++i) {
    int idx = i * 256 + t, c = idx >> 5, d = idx & 31;
    Ls[c][d] = gram[(size_t)bh * 1024 + idx] / (nq[c] * nk[d]) * tmp;
  }
  __syncthreads();
  if (t < 32) {
    float m = -1e30f;
#pragma unroll
    for (int d = 0; d < 32; ++d) m = fmaxf(m, Ls[t][d]);
    float s = 0.f;
#pragma unroll
    for (int d = 0; d < 32; ++d) s += expf(Ls[t][d] - m);
    float inv = 1.0f / s;
#pragma unroll
    for (int d = 0; d < 32; ++d) As[t][d] = expf(Ls[t][d] - m) * inv;
  }
  for (int i = 0; i < 24; ++i) {
    int idx = i * 256 + t, o = idx >> 5, c = idx & 31;
    wl[idx] = wp[o * 192 + h * 32 + c];
  }
  __syncthreads();
  for (int i = 0; i < 24; ++i) {
    int idx = i * 256 + t, o = idx >> 5, d = idx & 31;
    float a = 0.f;
#pragma unroll
    for (int c = 0; c < 32; ++c) a = fmaf(wl[o * 32 + c], As[c][d], a);
    W2[((size_t)(b * 192 + o)) * 192 + h * 32 + d] = f2bf(a);
  }
}

// ---------------------------------------------------------------------------
// K3: out[b][o][n] = sum_c W2[b][o][c] * v[b][c][n], MFMA 16x16x32 bf16.
// v in natural [b][c][n]; per ks-step stage 32x128 tile -> LDS transpose.
// Epilogue: LDS-transpose C so global stores are contiguous float4 runs.
// ---------------------------------------------------------------------------
__global__ __launch_bounds__(256) void k3_gemm(
    const u16* __restrict__ W2, const u16* __restrict__ vnat,
    float* __restrict__ out)
{
  __shared__ __align__(16) u16 b_tile[128 * VTS];
  __shared__ __align__(16) float cout[32 * 132];
  const int t = threadIdx.x, l = t & 63, w = t >> 6;
  const int bx = blockIdx.x;
  const int b  = bx >> 7, nb = bx & 127;
  const int arow = l & 15;
  const int kq8  = (l >> 4) * 8;
  const u16* w2b = W2 + (size_t)b * 192 * 192;
  const u16* vb  = vnat + ((size_t)b * CTOT) * HW;
  const int n0 = nb * 128;

  f32x4 acc[12][2] = {};

  for (int ks = 0; ks < 6; ++ks) {
    if (ks > 0) __syncthreads();
#pragma unroll
    for (int r2 = 0; r2 < 2; ++r2) {
      const int ch   = (t >> 4) + r2 * 16;
      const int nseg = (t & 15) * 8;
      short8 vv = *(const short8*)(vb + (size_t)(ks * 32 + ch) * HW + n0 + nseg);
#pragma unroll
      for (int j = 0; j < 8; ++j) b_tile[(nseg + j) * VTS + ch] = (u16)vv[j];
    }
    __syncthreads();

    short8 bf[2];
#pragma unroll
    for (int nt = 0; nt < 2; ++nt)
      bf[nt] = *(const short8*)&b_tile[(w * 32 + nt * 16 + arow) * VTS + kq8];
#pragma unroll
    for (int ot = 0; ot < 12; ++ot) {
      short8 af = *(const short8*)(w2b + (size_t)(ot * 16 + arow) * 192 + ks * 32 + kq8);
#pragma unroll
      for (int nt = 0; nt < 2; ++nt)
        acc[ot][nt] = __builtin_amdgcn_mfma_f32_16x16x32_bf16(af, bf[nt], acc[ot][nt], 0, 0, 0);
    }
  }

  float* __restrict__ ob = out + ((size_t)b * 192) * 16384;
#pragma unroll
  for (int og = 0; og < 6; ++og) {
    __syncthreads();
#pragma unroll
    for (int oi = 0; oi < 2; ++oi) {
#pragma unroll
      for (int nt = 0; nt < 2; ++nt)
#pragma unroll
        for (int rr = 0; rr < 4; ++rr) {
          const int o_l = oi * 16 + (l >> 4) * 4 + rr;
          const int n_l = w * 32 + nt * 16 + (l & 15);
          cout[o_l * 132 + n_l] = acc[og * 2 + oi][nt][rr];
        }
    }
    __syncthreads();
    const int o_l = t >> 3;
    const int o   = og * 32 + o_l;
#pragma unroll
    for (int c = 0; c < 4; ++c) {
      const int n = (t & 7) * 4 + c * 32;
      float4 v4;
      v4.x = cout[o_l * 132 + n + 0];
      v4.y = cout[o_l * 132 + n + 1];
      v4.z = cout[o_l * 132 + n + 2];
      v4.w = cout[o_l * 132 + n + 3];
      *(float4*)(ob + (size_t)o * 16384 + n0 + n) = v4;
    }
  }
}

// ---------------------------------------------------------------------------
extern "C" void kernel_launch(void* const* d_in, const int* in_sizes, int n_in,
                              void* d_out, int out_size, void* d_ws, size_t ws_size,
                              hipStream_t stream)
{
  const float* x    = (const float*)d_in[0];
  const float* y    = (const float*)d_in[1];
  const float* wdw  = (const float*)d_in[2];
  const float* wp   = (const float*)d_in[3];
  const float* temp = (const float*)d_in[4];

  char* ws = (char*)d_ws;
  const size_t QK = (size_t)NB * CTOT * HW * 2;   // 50,331,648 bytes per tensor
  u16*   qws  = (u16*)(ws);
  u16*   kws  = (u16*)(ws + QK);
  u16*   vws  = (u16*)(ws + 2 * QK);
  float* gram = (float*)(ws + 3 * QK);                  // 196608
  float* sqq  = (float*)(ws + 3 * QK + 196608);         // 6144
  float* sqk  = (float*)(ws + 3 * QK + 196608 + 6144);  // 6144
  u16*   W2   = (u16*)(ws + 3 * QK + 196608 + 12288);   // 8*192*192*2
  float* out  = (float*)d_out;

  hipMemsetAsync(ws + 3 * QK, 0, 208896, stream);
  kconv<<<3072, 256, 0, stream>>>(x, y, wdw, qws, kws, vws);
  k2a_gram<<<768, 256, 0, stream>>>(qws, kws, gram, sqq, sqk);
  k2b_w2<<<48, 256, 0, stream>>>(gram, sqq, sqk, wp, temp, W2);
  k3_gemm<<<1024, 256, 0, stream>>>(W2, vws, out);
}

// Round 14
// 168.107 us; speedup vs baseline: 1.0608x; 1.0608x over previous
//
#include <hip/hip_runtime.h>
#include <hip/hip_bf16.h>

#define DEV __device__ __forceinline__

typedef unsigned short u16;
typedef unsigned int u32;
typedef __attribute__((ext_vector_type(8))) short short8;
typedef __attribute__((ext_vector_type(4))) float f32x4;
typedef __attribute__((ext_vector_type(4), aligned(4))) float f32x4u;  // 4B-aligned vector load

DEV u16 f2bf(float f) {
  __hip_bfloat16 h = __float2bfloat16(f);   // RNE
  return *(u16*)&h;
}
DEV float bf2f_s(short s) { return __uint_as_float(((u32)(u16)s) << 16); }

#define NB 8
#define NH 6
#define CTOT 192
#define HW 16384
#define VTS 34     // k3 LDS n-row stride (u16): 17 dwords, coprime 32 banks

// ---------------------------------------------------------------------------
// KCONV v4: group-double-buffered streaming conv.
// R11-R13 all plateaued at ~100us with VGPR 28-32: the allocator targets max
// occupancy and collapses every source-level prefetch into load->wait->use
// (zero ILP, one exposed L2/L3 latency per row). Fix: __launch_bounds__(256,4)
// raises the VGPR cap to 128, and an 8-row GROUP double buffer (load group
// g+1 into B[10] while convolving A[10]) forces ~80 registers of pipeline
// state with a full group (~700cy) of load->use slack. Live set ~115 < 128.
// Row bounds via uniform scalar clamp + rare uniform branch; lane edge fixups
// precomputed; stores via base+imm offsets.
// ---------------------------------------------------------------------------
DEV float4 ldrow4(const float* __restrict__ rp, int offc, bool l0, bool l63) {
  f32x4u v = *(const f32x4u*)(rp + offc);
  float4 r = make_float4(v[0], v[1], v[2], v[3]);
  if (l0)  r = make_float4(0.f, v[0], v[1], v[2]);   // lane 0: {pad,0,1,2}
  if (l63) r = make_float4(v[1], v[2], v[3], 0.f);   // lane 63: {125,126,127,pad}
  return r;
}

__global__ __launch_bounds__(256, 4) void kconv(
    const float* __restrict__ x, const float* __restrict__ y,
    const float* __restrict__ wdw,
    u16* __restrict__ qws, u16* __restrict__ kws, u16* __restrict__ vws)
{
  const int t = threadIdx.x, lane = t & 63, w = t >> 6;
  const int tid  = blockIdx.x * 4 + w;   // 12288 wave-tasks
  const int iskv = tid & 1;              // interleave q / k+v within block
  const int task = tid >> 1;             // 0..6143
  const int b   = task / 768;
  const int rem = task - b * 768;
  const int gc  = rem >> 2;              // channel 0..191
  const int rg  = rem & 3;               // 32-row stripe
  const int r0  = rg * 32;

  const bool l0  = (lane == 0);
  const bool l63 = (lane == 63);
  const int  offc = l0 ? 0 : (l63 ? 124 : (2 * lane - 1));

  const float* __restrict__ in =
      (iskv ? y : x) + (((size_t)(b * CTOT + gc)) << 14);

  float w0[9], w1[9];
  if (!iskv) {
#pragma unroll
    for (int i = 0; i < 9; ++i) w0[i] = wdw[gc * 9 + i];
  } else {
#pragma unroll
    for (int i = 0; i < 9; ++i) {
      w0[i] = wdw[(CTOT + gc) * 9 + i];       // k
      w1[i] = wdw[(2 * CTOT + gc) * 9 + i];   // v
    }
  }

  u16* __restrict__ out0 =
      (iskv ? kws : qws) + (((size_t)(b * CTOT + gc)) << 14);
  u16* __restrict__ out1 = vws + (((size_t)(b * CTOT + gc)) << 14);

  // load 10 rows (8 outputs + 2 halo) of group g into buf
  #define LOADG(buf, g) { \
      const int Rb = r0 + (g) * 8 - 1; \
      _Pragma("unroll") \
      for (int i = 0; i < 10; ++i) { \
        const int ar  = Rb + i; \
        const int arc = ar < 0 ? 0 : (ar > 127 ? 127 : ar); \
        (buf)[i] = ldrow4(in + arc * 128, offc, l0, l63); \
        if (ar != arc) (buf)[i] = make_float4(0.f, 0.f, 0.f, 0.f); \
      } }

  // conv + store one row; taps px0=(x,y,z), px1=(y,z,w)
  #define CONVROW2(p0, p1, rm, rc, rp_) { \
      float o0, o1; \
      o0 = w0[0] * (rm).x; o0 = fmaf(w0[1], (rm).y, o0); o0 = fmaf(w0[2], (rm).z, o0); \
      o0 = fmaf(w0[3], (rc).x, o0); o0 = fmaf(w0[4], (rc).y, o0); o0 = fmaf(w0[5], (rc).z, o0); \
      o0 = fmaf(w0[6], (rp_).x, o0); o0 = fmaf(w0[7], (rp_).y, o0); o0 = fmaf(w0[8], (rp_).z, o0); \
      o1 = w0[0] * (rm).y; o1 = fmaf(w0[1], (rm).z, o1); o1 = fmaf(w0[2], (rm).w, o1); \
      o1 = fmaf(w0[3], (rc).y, o1); o1 = fmaf(w0[4], (rc).z, o1); o1 = fmaf(w0[5], (rc).w, o1); \
      o1 = fmaf(w0[6], (rp_).y, o1); o1 = fmaf(w0[7], (rp_).z, o1); o1 = fmaf(w0[8], (rp_).w, o1); \
      ((u32*)(p0))[lane] = ((u32)f2bf(o1) << 16) | (u32)f2bf(o0); \
      if (iskv) { \
        float v0, v1; \
        v0 = w1[0] * (rm).x; v0 = fmaf(w1[1], (rm).y, v0); v0 = fmaf(w1[2], (rm).z, v0); \
        v0 = fmaf(w1[3], (rc).x, v0); v0 = fmaf(w1[4], (rc).y, v0); v0 = fmaf(w1[5], (rc).z, v0); \
        v0 = fmaf(w1[6], (rp_).x, v0); v0 = fmaf(w1[7], (rp_).y, v0); v0 = fmaf(w1[8], (rp_).z, v0); \
        v1 = w1[0] * (rm).y; v1 = fmaf(w1[1], (rm).z, v1); v1 = fmaf(w1[2], (rm).w, v1); \
        v1 = fmaf(w1[3], (rc).y, v1); v1 = fmaf(w1[4], (rc).z, v1); v1 = fmaf(w1[5], (rc).w, v1); \
        v1 = fmaf(w1[6], (rp_).y, v1); v1 = fmaf(w1[7], (rp_).z, v1); v1 = fmaf(w1[8], (rp_).w, v1); \
        ((u32*)(p1))[lane] = ((u32)f2bf(v1) << 16) | (u32)f2bf(v0); \
      } }

  #define CONVG(buf, g) { \
      u16* __restrict__ o0b = out0 + (r0 + (g) * 8) * 128; \
      u16* __restrict__ o1b = out1 + (r0 + (g) * 8) * 128; \
      _Pragma("unroll") \
      for (int j = 0; j < 8; ++j) \
        CONVROW2(o0b + j * 128, o1b + j * 128, (buf)[j], (buf)[j + 1], (buf)[j + 2]); }

  float4 A[10], B[10];
  LOADG(A, 0);
  LOADG(B, 1);     // in flight while group 0 computes
  CONVG(A, 0);
  LOADG(A, 2);     // in flight while group 1 computes
  CONVG(B, 1);
  LOADG(B, 3);     // in flight while group 2 computes
  CONVG(A, 2);
  CONVG(B, 3);

  #undef LOADG
  #undef CONVROW2
  #undef CONVG
}

// ---------------------------------------------------------------------------
// K2a (verified R3): per (b,head) gram[c][d] = sum_n q[c][n]*k[d][n] via MFMA,
// plus sum-of-squares. grid 48x16 p-tiles, f32-atomic partials (pre-zeroed).
// ---------------------------------------------------------------------------
__global__ __launch_bounds__(256) void k2a_gram(
    const u16* __restrict__ qws, const u16* __restrict__ kws,
    float* __restrict__ gram, float* __restrict__ sqq, float* __restrict__ sqk)
{
  const int t = threadIdx.x, l = t & 63, w = t >> 6;
  const int bh = blockIdx.x >> 4, tile = blockIdx.x & 15;
  const int p0 = tile * 1024 + w * 256;
  const u16* qb = qws + (((size_t)bh) << 19);
  const u16* kb = kws + (((size_t)bh) << 19);
  const int row = l & 15;
  const int kq  = (l >> 4) * 8;

  f32x4 acc[2][2] = {};
  float sq[2] = {0.f, 0.f}, sk[2] = {0.f, 0.f};

  for (int ks = 0; ks < 8; ++ks) {
    const int p = p0 + ks * 32 + kq;
    short8 av[2], bv[2];
#pragma unroll
    for (int tc = 0; tc < 2; ++tc) {
      av[tc] = *(const short8*)(qb + (((size_t)(tc * 16 + row)) << 14) + p);
      bv[tc] = *(const short8*)(kb + (((size_t)(tc * 16 + row)) << 14) + p);
    }
#pragma unroll
    for (int tc = 0; tc < 2; ++tc) {
#pragma unroll
      for (int j = 0; j < 8; ++j) {
        float fa = bf2f_s(av[tc][j]); sq[tc] = fmaf(fa, fa, sq[tc]);
        float fb = bf2f_s(bv[tc][j]); sk[tc] = fmaf(fb, fb, sk[tc]);
      }
    }
#pragma unroll
    for (int tc = 0; tc < 2; ++tc)
#pragma unroll
      for (int td = 0; td < 2; ++td)
        acc[tc][td] = __builtin_amdgcn_mfma_f32_16x16x32_bf16(av[tc], bv[td], acc[tc][td], 0, 0, 0);
  }

#pragma unroll
  for (int tc = 0; tc < 2; ++tc)
#pragma unroll
    for (int td = 0; td < 2; ++td)
#pragma unroll
      for (int rr = 0; rr < 4; ++rr) {
        int c = tc * 16 + (l >> 4) * 4 + rr;
        int d = td * 16 + row;
        atomicAdd(gram + (size_t)bh * 1024 + c * 32 + d, acc[tc][td][rr]);
      }

#pragma unroll
  for (int tc = 0; tc < 2; ++tc) {
    sq[tc] += __shfl_xor(sq[tc], 16);
    sq[tc] += __shfl_xor(sq[tc], 32);
    sk[tc] += __shfl_xor(sk[tc], 16);
    sk[tc] += __shfl_xor(sk[tc], 32);
  }
  if ((l >> 4) == 0) {
#pragma unroll
    for (int tc = 0; tc < 2; ++tc) {
      atomicAdd(sqq + bh * 32 + tc * 16 + row, sq[tc]);
      atomicAdd(sqk + bh * 32 + tc * 16 + row, sk[tc]);
    }
  }
}

// ---------------------------------------------------------------------------
// K2b: logits = gram/(|q||k|)*temp, row-softmax, fold 1x1 proj:
//   W2[b][o][h*32+d] = sum_c wp[o][h*32+c] * A[c][d]  (bf16 out)
// ---------------------------------------------------------------------------
__global__ __launch_bounds__(256) void k2b_w2(
    const float* __restrict__ gram, const float* __restrict__ sqq,
    const float* __restrict__ sqk, const float* __restrict__ wp,
    const float* __restrict__ temp, u16* __restrict__ W2)
{
  __shared__ float Ls[32][33];
  __shared__ float As[32][33];
  __shared__ float wl[192 * 32];
  __shared__ float nq[32], nk[32];
  const int t = threadIdx.x;
  const int bh = blockIdx.x, b = bh / 6, h = bh % 6;
  const float tmp = temp[h];
  if (t < 32) nq[t] = fmaxf(sqrtf(sqq[bh * 32 + t]), 1e-12f);
  else if (t < 64) nk[t - 32] = fmaxf(sqrtf(sqk[bh * 32 + t - 32]), 1e-12f);
  __syncthreads();
#pragma unroll
  for (int i = 0; i < 4; ++i) {
    int idx = i * 256 + t, c = idx >> 5, d = idx & 31;
    Ls[c][d] = gram[(size_t)bh * 1024 + idx] / (nq[c] * nk[d]) * tmp;
  }
  __syncthreads();
  if (t < 32) {
    float m = -1e30f;
#pragma unroll
    for (int d = 0; d < 32; ++d) m = fmaxf(m, Ls[t][d]);
    float s = 0.f;
#pragma unroll
    for (int d = 0; d < 32; ++d) s += expf(Ls[t][d] - m);
    float inv = 1.0f / s;
#pragma unroll
    for (int d = 0; d < 32; ++d) As[t][d] = expf(Ls[t][d] - m) * inv;
  }
  for (int i = 0; i < 24; ++i) {
    int idx = i * 256 + t, o = idx >> 5, c = idx & 31;
    wl[idx] = wp[o * 192 + h * 32 + c];
  }
  __syncthreads();
  for (int i = 0; i < 24; ++i) {
    int idx = i * 256 + t, o = idx >> 5, d = idx & 31;
    float a = 0.f;
#pragma unroll
    for (int c = 0; c < 32; ++c) a = fmaf(wl[o * 32 + c], As[c][d], a);
    W2[((size_t)(b * 192 + o)) * 192 + h * 32 + d] = f2bf(a);
  }
}

// ---------------------------------------------------------------------------
// K3: out[b][o][n] = sum_c W2[b][o][c] * v[b][c][n], MFMA 16x16x32 bf16.
// v in natural [b][c][n]; per ks-step stage 32x128 tile -> LDS transpose.
// Epilogue: LDS-transpose C so global stores are contiguous float4 runs.
// ---------------------------------------------------------------------------
__global__ __launch_bounds__(256) void k3_gemm(
    const u16* __restrict__ W2, const u16* __restrict__ vnat,
    float* __restrict__ out)
{
  __shared__ __align__(16) u16 b_tile[128 * VTS];
  __shared__ __align__(16) float cout[32 * 132];
  const int t = threadIdx.x, l = t & 63, w = t >> 6;
  const int bx = blockIdx.x;
  const int b  = bx >> 7, nb = bx & 127;
  const int arow = l & 15;
  const int kq8  = (l >> 4) * 8;
  const u16* w2b = W2 + (size_t)b * 192 * 192;
  const u16* vb  = vnat + ((size_t)b * CTOT) * HW;
  const int n0 = nb * 128;

  f32x4 acc[12][2] = {};

  for (int ks = 0; ks < 6; ++ks) {
    if (ks > 0) __syncthreads();
#pragma unroll
    for (int r2 = 0; r2 < 2; ++r2) {
      const int ch   = (t >> 4) + r2 * 16;
      const int nseg = (t & 15) * 8;
      short8 vv = *(const short8*)(vb + (size_t)(ks * 32 + ch) * HW + n0 + nseg);
#pragma unroll
      for (int j = 0; j < 8; ++j) b_tile[(nseg + j) * VTS + ch] = (u16)vv[j];
    }
    __syncthreads();

    short8 bf[2];
#pragma unroll
    for (int nt = 0; nt < 2; ++nt)
      bf[nt] = *(const short8*)&b_tile[(w * 32 + nt * 16 + arow) * VTS + kq8];
#pragma unroll
    for (int ot = 0; ot < 12; ++ot) {
      short8 af = *(const short8*)(w2b + (size_t)(ot * 16 + arow) * 192 + ks * 32 + kq8);
#pragma unroll
      for (int nt = 0; nt < 2; ++nt)
        acc[ot][nt] = __builtin_amdgcn_mfma_f32_16x16x32_bf16(af, bf[nt], acc[ot][nt], 0, 0, 0);
    }
  }

  float* __restrict__ ob = out + ((size_t)b * 192) * 16384;
#pragma unroll
  for (int og = 0; og < 6; ++og) {
    __syncthreads();
#pragma unroll
    for (int oi = 0; oi < 2; ++oi) {
#pragma unroll
      for (int nt = 0; nt < 2; ++nt)
#pragma unroll
        for (int rr = 0; rr < 4; ++rr) {
          const int o_l = oi * 16 + (l >> 4) * 4 + rr;
          const int n_l = w * 32 + nt * 16 + (l & 15);
          cout[o_l * 132 + n_l] = acc[og * 2 + oi][nt][rr];
        }
    }
    __syncthreads();
    const int o_l = t >> 3;
    const int o   = og * 32 + o_l;
#pragma unroll
    for (int c = 0; c < 4; ++c) {
      const int n = (t & 7) * 4 + c * 32;
      float4 v4;
      v4.x = cout[o_l * 132 + n + 0];
      v4.y = cout[o_l * 132 + n + 1];
      v4.z = cout[o_l * 132 + n + 2];
      v4.w = cout[o_l * 132 + n + 3];
      *(float4*)(ob + (size_t)o * 16384 + n0 + n) = v4;
    }
  }
}

// ---------------------------------------------------------------------------
extern "C" void kernel_launch(void* const* d_in, const int* in_sizes, int n_in,
                              void* d_out, int out_size, void* d_ws, size_t ws_size,
                              hipStream_t stream)
{
  const float* x    = (const float*)d_in[0];
  const float* y    = (const float*)d_in[1];
  const float* wdw  = (const float*)d_in[2];
  const float* wp   = (const float*)d_in[3];
  const float* temp = (const float*)d_in[4];

  char* ws = (char*)d_ws;
  const size_t QK = (size_t)NB * CTOT * HW * 2;   // 50,331,648 bytes per tensor
  u16*   qws  = (u16*)(ws);
  u16*   kws  = (u16*)(ws + QK);
  u16*   vws  = (u16*)(ws + 2 * QK);
  float* gram = (float*)(ws + 3 * QK);                  // 196608
  float* sqq  = (float*)(ws + 3 * QK + 196608);         // 6144
  float* sqk  = (float*)(ws + 3 * QK + 196608 + 6144);  // 6144
  u16*   W2   = (u16*)(ws + 3 * QK + 196608 + 12288);   // 8*192*192*2
  float* out  = (float*)d_out;

  hipMemsetAsync(ws + 3 * QK, 0, 208896, stream);
  kconv<<<3072, 256, 0, stream>>>(x, y, wdw, qws, kws, vws);
  k2a_gram<<<768, 256, 0, stream>>>(qws, kws, gram, sqq, sqk);
  k2b_w2<<<48, 256, 0, stream>>>(gram, sqq, sqk, wp, temp, W2);
  k3_gemm<<<1024, 256, 0, stream>>>(W2, vws, out);
}